// Round 8
// baseline (2759.424 us; speedup 1.0000x reference)
//
#include <hip/hip_runtime.h>
#include <cstdint>

#define NPAT 8192
#define NBITS 4096

typedef float f32x2 __attribute__((ext_vector_type(2)));
typedef unsigned int u32;

// ws layout:
//   [0, 4 MiB)      : Bt[i][t] delta-sign bits, uint32, i in [0,4096), t in [0,256)
//                     thread t: b = t>>2, a = t&3
//                     bit k     (k=0..15): sign of d for elem p = 128b + 2a     + 8k
//                     bit 16+k           : sign of d for elem p = 128b + 2a + 1 + 8k
//                     where d = -2*state[i]*W[p][i]  (state = ORIGINAL state; valid
//                     because perm visits each i exactly once). sign bit set => d<0.
//   [4 MiB, +32 KiB): h0 float[8192] (exact integers)

__global__ void pack_kernel(const float* __restrict__ W, const float* __restrict__ state,
                            uint32_t* __restrict__ Bt) {
    int b = blockIdx.x & 63;
    int i = (blockIdx.x >> 6) * 256 + threadIdx.x;
    uint32_t spre = (__float_as_uint(state[i]) >> 31) ^ 1u;
    uint32_t wd0 = 0, wd1 = 0, wd2 = 0, wd3 = 0;
    const float* base = W + (size_t)(128 * b) * NBITS + i;
    #pragma unroll
    for (int q = 0; q < 128; ++q) {
        uint32_t bit = (__float_as_uint(base[(size_t)q * NBITS]) >> 31) ^ spre;  // coalesced
        int j = q & 7, k = q >> 3;
        int a = j >> 1, hi = j & 1;
        uint32_t add = bit << (16 * hi + k);
        if (a == 0) wd0 |= add;
        else if (a == 1) wd1 |= add;
        else if (a == 2) wd2 |= add;
        else wd3 |= add;
    }
    *(uint4*)(Bt + (size_t)i * 256 + 4 * b) = make_uint4(wd0, wd1, wd2, wd3);
}

__global__ void gemv_kernel(const float* __restrict__ W, const float* __restrict__ state,
                            float* __restrict__ h0) {
    int wid = threadIdx.x >> 6, lane = threadIdx.x & 63;
    int p = blockIdx.x * 4 + wid;
    const float* row = W + (size_t)p * NBITS;
    float acc = 0.f;
    for (int k = lane; k < NBITS; k += 64) acc += row[k] * state[k];
    #pragma unroll
    for (int d = 1; d < 64; d <<= 1) acc += __shfl_xor(acc, d, 64);
    if (lane == 0) h0[p] = acc;
}

// Exact numpy-pairwise tree (mapping proven bit-exact in R1-R7, absmax 0).
__device__ __forceinline__ float tree_reduce(float x) {
    x = __uint_as_float(__builtin_amdgcn_update_dpp(__float_as_uint(x), __float_as_uint(x),
                                                    0xB1, 0xf, 0xf, false)) + x;   // quad xor1
    x = __uint_as_float(__builtin_amdgcn_update_dpp(__float_as_uint(x), __float_as_uint(x),
                                                    0x4E, 0xf, 0xf, false)) + x;   // quad xor2
    x = __uint_as_float(__builtin_amdgcn_update_dpp(__float_as_uint(x), __float_as_uint(x),
                                                    0x141, 0xf, 0xf, false)) + x;  // b^1
    x = __uint_as_float(__builtin_amdgcn_update_dpp(__float_as_uint(x), __float_as_uint(x),
                                                    0x140, 0xf, 0xf, false)) + x;  // b^2
#if __has_builtin(__builtin_amdgcn_permlane16_swap)
    {
        auto pr = __builtin_amdgcn_permlane16_swap(__float_as_uint(x), __float_as_uint(x),
                                                   false, false);
        x = __uint_as_float(pr[0]) + __uint_as_float(pr[1]);                        // lane^16
    }
#else
    x = __int_as_float(__builtin_amdgcn_ds_swizzle(__float_as_int(x), 0x401F)) + x;
#endif
#if __has_builtin(__builtin_amdgcn_permlane32_swap)
    {
        auto pr = __builtin_amdgcn_permlane32_swap(__float_as_uint(x), __float_as_uint(x),
                                                   false, false);
        x = __uint_as_float(pr[0]) + __uint_as_float(pr[1]);                        // lane^32
    }
#else
    x += __shfl_xor(x, 32, 64);
#endif
    return x;
}

// decode one +/-2.0f from bit k (lo) or bit 16+k (hi) of word w:
//   lo: (w << (31-k)) & 0x80000000 | 0x40000000   (v_lshlrev + v_and_or, inline consts)
#define DLO(w, k) __uint_as_float((((w) << (31 - (k))) & 0x80000000u) | 0x40000000u)
#define DHI(w, k) __uint_as_float((((w) << (15 - (k))) & 0x80000000u) | 0x40000000u)

__launch_bounds__(256, 1)
__global__ void seq_kernel(const uint32_t* __restrict__ Bt, const float* __restrict__ h0,
                           const float* __restrict__ state, const int* __restrict__ perm,
                           float* __restrict__ out) {
    __shared__ alignas(16) float part[2][4][4];   // [buf][wave][cand A,B,C,pad]
    __shared__ alignas(16) int2 pv[NBITS];        // (i, bits(state[i])) in visit order

    const int t = threadIdx.x;
    const int b = t >> 2, a = t & 3;
    const int lane = t & 63, wid = t >> 6;

    for (int q = t; q < NBITS; q += 256) {
        int ii = perm[q];
        pv[q] = make_int2(ii, __float_as_int(state[ii]));
    }

    float hl[16], hh[16];
    #pragma unroll
    for (int k = 0; k < 16; ++k) {
        f32x2 p2 = *(const f32x2*)(h0 + 128 * b + 2 * a + 8 * k);
        hl[k] = p2.x; hh[k] = p2.y;
    }

    __syncthreads();

    // words for rounds 0,1 (steps 0..3); slot r&1 holds round r's pair
    u32 wA[2], wB[2];
    wA[0] = Bt[(size_t)pv[0].x * 256 + t];
    wB[0] = Bt[(size_t)pv[1].x * 256 + t];
    wA[1] = Bt[(size_t)pv[2].x * 256 + t];
    wB[1] = Bt[(size_t)pv[3].x * 256 + t];

    float Sprev;
    {   // S(h_0), numpy-exact; uses buf 1 (round 0 uses buf 0 -> no same-buf race)
        float ral, rah;
        #pragma unroll
        for (int k = 0; k < 16; ++k) {
            float xl = fmaxf(hl[k], 0.f), xh = fmaxf(hh[k], 0.f);
            ral = k ? fmaf(xl, xl, ral) : xl * xl;
            rah = k ? fmaf(xh, xh, rah) : xh * xh;
        }
        float red = tree_reduce(ral + rah);
        if (lane == 0) part[1][wid][0] = red;
        asm volatile("s_waitcnt lgkmcnt(0)\n\ts_barrier" ::: "memory");
        Sprev = (part[1][0][0] + part[1][1][0]) + (part[1][2][0] + part[1][3][0]);
    }

    for (int rb = 0; rb < NBITS / 2; rb += 2) {
        #pragma unroll
        for (int u = 0; u < 2; ++u) {
            const int rr = rb + u;             // round = steps (2rr, 2rr+1)
            const int s  = 2 * rr;
            const u32 w0 = wA[u], w1 = wB[u];

            // this round's (i0,v0,i1,v1) — one ds_read_b128 issued early
            int4 pvc = *(const int4*)(&pv[s]);

            // 3 candidates, inline decode, scalar chains (numpy order, k ascending)
            float ral, rah, rbl, rbh, rcl, rch;
            #pragma unroll
            for (int k = 0; k < 16; ++k) {
                float d0l = DLO(w0, k), d0h = DHI(w0, k);
                float d1l = DLO(w1, k), d1h = DHI(w1, k);
                float val = hl[k] + d0l, vah = hh[k] + d0h;
                float vbl = hl[k] + d1l, vbh = hh[k] + d1h;
                float vcl = val + d1l,  vch = vah + d1h;   // ref association
                float xal = fmaxf(val, 0.f), xah = fmaxf(vah, 0.f);
                float xbl = fmaxf(vbl, 0.f), xbh = fmaxf(vbh, 0.f);
                float xcl = fmaxf(vcl, 0.f), xch = fmaxf(vch, 0.f);
                if (k == 0) {
                    ral = xal * xal; rah = xah * xah;
                    rbl = xbl * xbl; rbh = xbh * xbh;
                    rcl = xcl * xcl; rch = xch * xch;
                } else {
                    ral = fmaf(xal, xal, ral); rah = fmaf(xah, xah, rah);
                    rbl = fmaf(xbl, xbl, rbl); rbh = fmaf(xbh, xbh, rbh);
                    rcl = fmaf(xcl, xcl, rcl); rch = fmaf(xch, xch, rch);
                }
            }
            float Ra = tree_reduce(ral + rah);
            float Rb = tree_reduce(rbl + rbh);
            float Rc = tree_reduce(rcl + rch);
            if (lane == 0)
                *(float4*)(&part[u][wid][0]) = make_float4(Ra, Rb, Rc, 0.0f);
            asm volatile("s_waitcnt lgkmcnt(0)\n\ts_barrier" ::: "memory");

            float4 p0 = *(const float4*)(&part[u][0][0]);
            float4 p1 = *(const float4*)(&part[u][1][0]);
            float4 p2 = *(const float4*)(&part[u][2][0]);
            float4 p3 = *(const float4*)(&part[u][3][0]);

            // refill slot u with round rr+2's words (2-round slack)
            int li = (s + 4 < NBITS) ? s + 4 : NBITS - 2;   // even -> 16B aligned
            int4 pvn = *(const int4*)(&pv[li]);
            wA[u] = Bt[(size_t)pvn.x * 256 + t];
            wB[u] = Bt[(size_t)pvn.z * 256 + t];

            float Sa = (p0.x + p1.x) + (p2.x + p3.x);
            float Sb = (p0.y + p1.y) + (p2.y + p3.y);
            float Sc = (p0.z + p1.z) + (p2.z + p3.z);

            // accept iff E_new < E_prev  <=>  S_new > S_prev (ties reject)
            bool acc0 = Sa > Sprev;
            bool acc1 = acc0 ? (Sc > Sa) : (Sb > Sprev);
            Sprev = acc1 ? (acc0 ? Sc : Sb) : (acc0 ? Sa : Sprev);

            if (t == 0) {
                float v0 = __int_as_float(pvc.y), v1 = __int_as_float(pvc.w);
                out[pvc.x] = acc0 ? -v0 : v0;
                out[pvc.z] = acc1 ? -v1 : v1;
            }

            // h-update: acc0/acc1 are wave-uniform -> scalar branches; most
            // rounds skip entirely. Recomputed deltas are bit-identical (+/-2).
            int a0 = __builtin_amdgcn_readfirstlane(acc0 ? 1 : 0);
            int a1 = __builtin_amdgcn_readfirstlane(acc1 ? 1 : 0);
            if (a0) {
                if (a1) {
                    #pragma unroll
                    for (int k = 0; k < 16; ++k) {   // (h+d0)+d1, exact ints
                        hl[k] = (hl[k] + DLO(w0, k)) + DLO(w1, k);
                        hh[k] = (hh[k] + DHI(w0, k)) + DHI(w1, k);
                    }
                } else {
                    #pragma unroll
                    for (int k = 0; k < 16; ++k) {
                        hl[k] = hl[k] + DLO(w0, k);
                        hh[k] = hh[k] + DHI(w0, k);
                    }
                }
            } else if (a1) {
                #pragma unroll
                for (int k = 0; k < 16; ++k) {
                    hl[k] = hl[k] + DLO(w1, k);
                    hh[k] = hh[k] + DHI(w1, k);
                }
            }
        }
    }
}

extern "C" void kernel_launch(void* const* d_in, const int* in_sizes, int n_in,
                              void* d_out, int out_size, void* d_ws, size_t ws_size,
                              hipStream_t stream) {
    const float* W     = (const float*)d_in[0];
    const float* state = (const float*)d_in[1];
    const int*   perm  = (const int*)d_in[2];
    float*       out   = (float*)d_out;

    uint32_t* Bt = (uint32_t*)d_ws;
    float*    h0 = (float*)((char*)d_ws + (size_t)4096 * 256 * 4);

    pack_kernel<<<1024, 256, 0, stream>>>(W, state, Bt);
    gemv_kernel<<<2048, 256, 0, stream>>>(W, state, h0);
    seq_kernel<<<1, 256, 0, stream>>>(Bt, h0, state, perm, out);
}